// Round 9
// baseline (228.210 us; speedup 1.0000x reference)
//
#include <hip/hip_runtime.h>
#include <cstdint>
#include <math.h>

#define NBATCH 8
#define NANCH 262144
#define TOPK 6000
#define OUTK 1000
#define CAP 16384
#define ROWS 6016          // TOPK padded to 94*64 (boxes/areas stride)
#define MROWS 2048         // masked NMS window: rows/cols with precomputed mask
#define MWORDS 32          // MROWS/64
#define NT2 528            // upper-tri tiles in window: 32*33/2
#define NBIN 8192          // fine-rank bins: (bucket-m)*2048 + float bits [19:9]

using u32 = uint32_t;
using u64 = unsigned long long;

// fine bin of a candidate key, given marginal 12-bit bucket m. Monotone non-decreasing
// in key (lexicographic on float bits [31:9], clamped at top) -> exact rank decomposition:
// rank(k) = #{k' : bin(k') > bin(k)} + #{k' : bin equal && k' > k}   (keys are unique).
__device__ inline u32 binof(u64 key, u32 m) {
    u32 hb  = (u32)(key >> 52);            // float bits [31:20] (>= m for all stored keys)
    u32 mid = (u32)(key >> 41) & 0x7FFu;   // float bits [19:9]
    u32 bi = (hb - m) * 2048u + mid;
    return bi > (NBIN - 1) ? (NBIN - 1) : bi;
}

// ---------------- coarse top-k threshold: one 12-bit histogram pass ----------------
__global__ void hist_kernel(const float* __restrict__ cls, u32* __restrict__ hist) {
    __shared__ u32 lh[4096];
    int b = blockIdx.y, t = threadIdx.x;
    for (int i = t; i < 4096; i += 256) lh[i] = 0;
    __syncthreads();
    const float4* p4 = (const float4*)(cls + (size_t)b * NANCH * 2);
    const int P = NANCH / 2;
    for (int p = blockIdx.x * 256 + t; p < P; p += gridDim.x * 256) {
        float4 v = p4[p];
        atomicAdd(&lh[__float_as_uint(v.y) >> 20], 1);
        atomicAdd(&lh[__float_as_uint(v.w) >> 20], 1);
    }
    __syncthreads();
    for (int i = t; i < 4096; i += 256) { u32 c = lh[i]; if (c) atomicAdd(&hist[b * 4096 + i], c); }
}

// ---------------- compact: inline threshold scan + LDS staging, 1 atomic/block ----------
__global__ void compact_kernel(const float* __restrict__ cls, const u32* __restrict__ hist,
                               u32* __restrict__ meta, u64* __restrict__ cand) {
    __shared__ u64 buf[4096];
    __shared__ u32 ts[256];
    __shared__ u32 thr, lc, gbase;
    int b = blockIdx.y, t = threadIdx.x;
    if (t == 0) lc = 0;
    const u32* h = hist + b * 4096;
    u32 s = 0;
    for (int k = 0; k < 16; k++) s += h[t * 16 + k];
    ts[t] = s; __syncthreads();
    u32 suf = 0;
    for (int t2 = t + 1; t2 < 256; t2++) suf += ts[t2];
    if (suf < TOPK && suf + s >= TOPK) {
        u32 a = suf;
        for (int k = 15; k >= 0; k--) {
            u32 c = h[t * 16 + k];
            if (a + c >= TOPK) { thr = (u32)(t * 16 + k) << 20; break; }
            a += c;
        }
    }
    __syncthreads();
    u32 T = thr;
    if (t == 0) meta[56 + b] = T >> 20;              // marginal bucket m (same in all blocks)
    const float4* p4 = (const float4*)(cls + (size_t)b * NANCH * 2);
    const int P = NANCH / 2;
    for (int p = blockIdx.x * 256 + t; p < P; p += gridDim.x * 256) {
        float4 v = p4[p];
        u32 k0 = __float_as_uint(v.y), k1 = __float_as_uint(v.w);
        u32 n0 = 2u * (u32)p, n1 = n0 + 1u;
        if (k0 >= T) { u32 q = atomicAdd(&lc, 1u); buf[q] = ((u64)k0 << 32) | (u32)(~n0); }
        if (k1 >= T) { u32 q = atomicAdd(&lc, 1u); buf[q] = ((u64)k1 << 32) | (u32)(~n1); }
    }
    __syncthreads();
    if (t == 0) gbase = atomicAdd(&meta[48 + b], lc);
    __syncthreads();
    u32 base = gbase, n = lc;
    for (u32 j = t; j < n; j += 256) {
        u32 d = base + j;
        if (d < CAP) cand[(size_t)b * CAP + d] = buf[j];
    }
}

// ---------------- fused rank machinery: LDS histogram + scan + scatter + exact rank -----
// One block per batch (1024 threads). The 8192-bin fine histogram lives entirely in LDS:
// build from cand -> hierarchical descending suffix-scan (8 bins/thread + wave suffix +
// cross-wave suffix) -> scatter cand into bin-grouped global array -> same-block rank
// (neighbor scan within bin run) -> decode anchors/bbox -> write boxes/areas.
// Replaces 3 dispatches (scan/scatter/rank) and all hist16 global traffic.
__global__ __launch_bounds__(1024) void group_rank_kernel(
                            const u64* __restrict__ cand, const u32* __restrict__ meta,
                            const float* __restrict__ anchors, const float* __restrict__ bbox,
                            u64* __restrict__ grouped,
                            float4* __restrict__ boxes, float* __restrict__ areas) {
    __shared__ u32 lh[NBIN];                         // 32 KB: hist -> bases -> slot counters
    __shared__ u32 part[1024];
    __shared__ u32 wsum[16];
    int b = blockIdx.x, t = threadIdx.x;
    int wv = t >> 6, l = t & 63;
    u32 cnt = meta[48 + b]; if (cnt > CAP) cnt = CAP;
    u32 m = meta[56 + b];
    const u64* cb = cand + (size_t)b * CAP;
    u64* gb = grouped + (size_t)b * CAP;
    if (t < ROWS - TOPK) {                           // zero-pad rows 6000..6015
        boxes[(size_t)b * ROWS + TOPK + t] = make_float4(0.f, 0.f, 0.f, 0.f);
        areas[(size_t)b * ROWS + TOPK + t] = 0.f;
    }
    // 1) zero + build LDS histogram over stored keys
    #pragma unroll
    for (int k = 0; k < NBIN / 1024; k++) lh[t + k * 1024] = 0;
    __syncthreads();
    for (u32 i = t; i < cnt; i += 1024) atomicAdd(&lh[binof(cb[i], m)], 1u);
    __syncthreads();
    // 2) descending suffix scan: base[i] = #keys in bins > i. Thread t owns bins [8t, 8t+8).
    u32 s = 0;
    #pragma unroll
    for (int k = 0; k < 8; k++) s += lh[t * 8 + k];
    part[t] = s;
    __syncthreads();
    u32 wsuf = 0;                                    // suffix within wave (lanes > l)
    for (int k = l + 1; k < 64; k++) wsuf += part[(wv << 6) + k];
    if (l == 0) wsum[wv] = wsuf + part[wv << 6];     // total of this wave's 64 partials
    __syncthreads();
    u32 cur = wsuf;
    for (int k = wv + 1; k < 16; k++) cur += wsum[k];
    #pragma unroll
    for (int k = 7; k >= 0; k--) {                   // descending within my 8 bins
        u32 c = lh[t * 8 + k];
        lh[t * 8 + k] = cur;
        cur += c;
    }
    __syncthreads();
    // 3) scatter into bin-grouped order (slot = LDS atomic on base)
    for (u32 i = t; i < cnt; i += 1024) {
        u64 key = cb[i];
        u32 p = atomicAdd(&lh[binof(key, m)], 1u);
        if (p < CAP) gb[p] = key;                    // p < cnt always; defensive
    }
    __threadfence_block();                           // block-visible global writes
    __syncthreads();
    // 4) exact rank: bin run [s,e) around position p; base = run start
    for (u32 pi = t; pi < cnt; pi += 1024) {
        u64 key = gb[pi];
        u32 bi = binof(key, m);
        int sp = (int)pi;
        while (sp > 0 && binof(gb[sp - 1], m) == bi) sp--;
        u32 r = 0;
        int q = sp;
        while (q < (int)cnt) {
            u64 kq = gb[q];
            if (binof(kq, m) != bi) break;
            r += (kq > key) ? 1u : 0u;
            q++;
        }
        u32 rank = (u32)sp + r;
        if (rank < TOPK) {
            u32 idx = ~(u32)(key & 0xFFFFFFFFull);
            size_t off = ((size_t)b * NANCH + idx) * 4;
            const float4 a = *(const float4*)(anchors + off);
            const float4 d = *(const float4*)(bbox + off);
            float h = a.z - a.x, w = a.w - a.y;
            float cy = a.x + 0.5f * h, cx = a.y + 0.5f * w;
            float dy = d.x * 0.1f, dx = d.y * 0.1f, dh = d.z * 0.2f, dw = d.w * 0.2f;
            cy = cy + dy * h; cx = cx + dx * w;
            h = h * (float)exp((double)dh);
            w = w * (float)exp((double)dw);
            float y1 = cy - 0.5f * h, x1 = cx - 0.5f * w;
            float y2 = cy + 0.5f * h, x2 = cx + 0.5f * w;
            y1 = fminf(fmaxf(y1, 0.f), 1.f); x1 = fminf(fmaxf(x1, 0.f), 1.f);
            y2 = fminf(fmaxf(y2, 0.f), 1.f); x2 = fminf(fmaxf(x2, 0.f), 1.f);
            boxes[(size_t)b * ROWS + rank] = make_float4(y1, x1, y2, x2);
            areas[(size_t)b * ROWS + rank] = (y2 - y1) * (x2 - x1);  // same rounding as ref
        }
    }
}

// ---------------- cross-lane helpers ----------------
__device__ inline u64 wave_or64(u64 x) {
    u32 lo = (u32)x, hi = (u32)(x >> 32);
    lo |= __builtin_amdgcn_ds_swizzle(lo, 0x041F); hi |= __builtin_amdgcn_ds_swizzle(hi, 0x041F);
    lo |= __builtin_amdgcn_ds_swizzle(lo, 0x081F); hi |= __builtin_amdgcn_ds_swizzle(hi, 0x081F);
    lo |= __builtin_amdgcn_ds_swizzle(lo, 0x101F); hi |= __builtin_amdgcn_ds_swizzle(hi, 0x101F);
    lo |= __builtin_amdgcn_ds_swizzle(lo, 0x201F); hi |= __builtin_amdgcn_ds_swizzle(hi, 0x201F);
    lo |= __builtin_amdgcn_ds_swizzle(lo, 0x401F); hi |= __builtin_amdgcn_ds_swizzle(hi, 0x401F);
    u32 l0 = (u32)__builtin_amdgcn_readlane((int)lo, 0)  | (u32)__builtin_amdgcn_readlane((int)lo, 32);
    u32 h0 = (u32)__builtin_amdgcn_readlane((int)hi, 0)  | (u32)__builtin_amdgcn_readlane((int)hi, 32);
    return ((u64)h0 << 32) | l0;
}

// ---------------- NMS phase A: mask only the first MROWS rows/cols (528 tiles) ----------
// Exact decision: RN(inter/uni) > 0.7f  <=>  inter >= MID*uni (reals), MID = 0.7f + 2^-25.
// Fast f32 path: d = fma(uni,-0.7f,inter); |d| > 2^-18*uni => sign decides. Waves with any
// borderline col (rare) redo the whole tile with an exact-sign f64 fma.
// DIAGONAL tiles are stored COLUMN-major (lane l = column l: bit r = "row r suppresses
// col l", r < l) plus a self-bit at l — consumed only by nms_seq's fixpoint solve, which
// then needs no cross-lane readlane per step. Off-diag tiles stay row-major.
__global__ __launch_bounds__(256) void nms_mask_kernel(const float4* __restrict__ boxes,
                                                       const float* __restrict__ areas,
                                                       u64* __restrict__ Mt) {
    const float  EPS  = 3.8146972656e-06f;                       // 2^-18
    const double MIDD = (double)0.7f + 2.9802322387695312e-08;   // midpoint to nextup(0.7f)
    __shared__ float4 scol[4][64];
    __shared__ float  sare[4][64];
    int b = blockIdx.y;
    int wv = threadIdx.x >> 6, l = threadIdx.x & 63;
    int tid = blockIdx.x * 4 + wv;                               // linear upper-tri tile id
    if (tid >= NT2) return;                                      // wave-private LDS: safe
    // decode tid -> (cb, rt), rt <= cb, tid = cb*(cb+1)/2 + rt
    int cb = (int)((sqrt(8.0 * (double)tid + 1.0) - 1.0) * 0.5);
    while ((cb + 1) * (cb + 2) / 2 <= tid) cb++;
    while (cb * (cb + 1) / 2 > tid) cb--;
    int rt = tid - cb * (cb + 1) / 2;
    const float4* bx = boxes + (size_t)b * ROWS;
    const float*  ar = areas + (size_t)b * ROWS;
    scol[wv][l] = bx[cb * 64 + l];               // stage this wave's 64 col boxes (wave-sync)
    sare[wv][l] = ar[cb * 64 + l];
    int row = rt * 64 + l;
    float4 r4 = bx[row];
    float  rar = ar[row];
    u32 wlo = 0, whi = 0; u64 unc = 0;
    #pragma unroll
    for (int c = 63; c >= 0; c--) {              // full unroll, shift-or accumulation
        float4 c4 = scol[wv][c];                 // broadcast ds_read_b128 (no conflict)
        float  caf = sare[wv][c];
        float y1 = fmaxf(r4.x, c4.x), x1 = fmaxf(r4.y, c4.y);
        float y2 = fminf(r4.z, c4.z), x2 = fminf(r4.w, c4.w);
        float inter = fmaxf(y2 - y1, 0.f) * fmaxf(x2 - x1, 0.f);
        float uni = ((rar + caf) - inter) + 1e-9f;   // assoc matches reference
        float d = fmaf(uni, -0.7f, inter);
        float tt = uni * EPS;
        u32 sup = (d > tt) ? 1u : 0u;
        unc |= __ballot(fabsf(d) <= tt);
        if (c >= 32) whi = (whi << 1) | sup;
        else         wlo = (wlo << 1) | sup;
    }
    if (unc) {                                   // wave-uniform, rare
        wlo = 0; whi = 0;
        for (int c = 63; c >= 0; c--) {
            float4 c4 = scol[wv][c]; float caf = sare[wv][c];
            float y1 = fmaxf(r4.x, c4.x), x1 = fmaxf(r4.y, c4.y);
            float y2 = fminf(r4.z, c4.z), x2 = fminf(r4.w, c4.w);
            float inter = fmaxf(y2 - y1, 0.f) * fmaxf(x2 - x1, 0.f);
            float uni = ((rar + caf) - inter) + 1e-9f;
            double td = fma((double)uni, -MIDD, (double)inter);
            u32 sup = (td >= 0.0) ? 1u : 0u;     // exact sign; tie -> suppress (RN ties up)
            if (c >= 32) whi = (whi << 1) | sup;
            else         wlo = (wlo << 1) | sup;
        }
    }
    u64 w = ((u64)whi << 32) | wlo;
    if (cb == rt) {
        w &= (l < 63) ? (~0ull << (l + 1)) : 0ull;   // cols > row only (row-major view)
        // ballot-transpose: column c2's word = ballot over lanes(rows) of bit c2.
        u64 tw = 0;
        for (int c2 = 0; c2 < 64; c2++) {
            u64 bc = __ballot((u32)((w >> c2) & 1ull) != 0u);
            if (l == c2) tw = bc;
        }
        w = tw | (1ull << l);                        // self-bit (not below(l): harmless)
    }
    Mt[((size_t)b * MWORDS + cb) * MROWS + row] = w;           // coalesced full-line store
}

// ---------------- NMS phase B: masked sweep over first MROWS, exact fallback beyond -----
// Greedy kept-set per chunk = UNIQUE fixpoint of K = F(K), F(K) = {r in alive :
// col_r & K & below(r) == 0} (suppression is lower->higher index only, so the relation
// is a DAG; uniqueness by induction on row index). Fixpoint iteration from K0 = alive
// converges in <= max suppression-chain length (sparse suppression => ~1-3 iterations),
// replacing ~64 serial pick-steps per chunk with ~2-3 ballots.
__global__ __launch_bounds__(64) void nms_seq_kernel(const float4* __restrict__ boxes,
                                                     const float* __restrict__ areas,
                                                     const u64* __restrict__ Mt,
                                                     float* __restrict__ out) {
    const double MIDD = (double)0.7f + 2.9802322387695312e-08;
    __shared__ u32 keptIdx[1024];
    __shared__ float4 sbox[1024];
    __shared__ float  skar[1024];
    int b = blockIdx.x, l = threadIdx.x;
    const u64* Mb = Mt + (size_t)b * MWORDS * MROWS;  // Mb[word*MROWS + row]
    const float4* bx = boxes + (size_t)b * ROWS;
    const float*  ar = areas + (size_t)b * ROWS;
    float4* ob = (float4*)(out + (size_t)b * OUTK * 4);
    const u64 below = (1ull << l) - 1ull;             // bits strictly under this lane
    int kept = 0;
    u64 rw = 0;
    u64 dw0 = Mb[l];                                  // diag word (col-major) of chunk 0
    float4 vb0 = bx[l];  float va0 = ar[l];
    u64 X0 = Mb[(size_t)MROWS + l];                   // chunk-0 rows -> word 1
    u64 dw1 = Mb[(size_t)MROWS + 64 + l];             // diag word (col-major) of chunk 1
    float4 vb1 = bx[64 + l]; float va1 = ar[64 + l];
    u64 X1 = Mb[(size_t)2 * MROWS + 64 + l];          // chunk-1 rows -> word 2
    u64 gp = 0;                                       // per-lane PARTIAL lookahead OR
    for (int c = 0; c < MWORDS; c++) {
        int base = c * 64;
        u64 alive = ~rw;                              // all MROWS rows valid (< TOPK)
        u64 K = alive;                                // fixpoint solve (uniform value)
        while (true) {
            u64 Kn = alive & ~__ballot((dw0 & K & below) != 0ull);
            if (Kn == K) break;                       // true fixpoint = greedy kept set
            K = Kn;
        }
        int avail = OUTK - kept;
        int nk  = (int)__popcll(K);
        int pos = (int)__popcll(K & below);           // per-lane output offset
        u32 keptme = (u32)((K >> l) & 1ull);
        if (nk > avail) keptme &= (u32)(pos < avail); // exact greedy stop at OUTK
        if (keptme) {
            int opos = kept + pos;
            ob[opos] = vb0;
            keptIdx[opos] = (u32)(base + l);
            sbox[opos] = vb0;                         // mirror for potential fallback
            skar[opos] = va0;
        }
        kept += (nk < avail) ? nk : avail;
        if (kept >= OUTK || c + 1 >= MWORDS) break;
        rw = wave_or64((keptme ? X0 : 0ull) | gp);    // deferred xk + lookahead, one reduce
        __syncthreads();                              // keptIdx visible for gather
        u64 dw2 = 0, X2 = 0; float4 vb2 = make_float4(0.f, 0.f, 0.f, 0.f); float va2 = 0.f;
        u64 gpn = 0;
        if (c + 2 < MWORDS) {
            int nb2 = base + 128;
            dw2 = Mb[(size_t)(c + 2) * MROWS + nb2 + l];
            vb2 = bx[nb2 + l]; va2 = ar[nb2 + l];
            if (c + 3 < MWORDS) X2 = Mb[(size_t)(c + 3) * MROWS + nb2 + l];
            int K2g = kept;
            if (K2g > 0) {
                #pragma unroll
                for (int u = 0; u < 16; u++) {
                    int k = l + (u << 6);
                    u32 idx = keptIdx[(k < K2g) ? k : K2g - 1];
                    gpn |= Mb[(size_t)(c + 2) * MROWS + idx];
                }
            }
        }
        dw0 = dw1; X0 = X1; vb0 = vb1; va0 = va1;
        dw1 = dw2; X1 = X2; vb1 = vb2; va1 = va2;
        gp = gpn;
    }
    // exact on-demand fallback for rows beyond the masked window (expected never taken)
    if (kept < OUTK) {
        __syncthreads();
        for (int i = MROWS; i < TOPK && kept < OUTK; i++) {
            float4 c4 = bx[i]; float ca = ar[i];      // uniform load
            int sup = 0;
            for (int j = l; j < kept; j += 64) {
                float4 kb = sbox[j]; float ka = skar[j];
                float y1 = fmaxf(kb.x, c4.x), x1 = fmaxf(kb.y, c4.y);
                float y2 = fminf(kb.z, c4.z), x2 = fminf(kb.w, c4.w);
                float inter = fmaxf(y2 - y1, 0.f) * fmaxf(x2 - x1, 0.f);
                float uni = ((ka + ca) - inter) + 1e-9f;
                double td = fma((double)uni, -MIDD, (double)inter);
                sup |= (td >= 0.0) ? 1 : 0;
            }
            if (!__any(sup)) {
                if (l == 0) { ob[kept] = c4; sbox[kept] = c4; skar[kept] = ca; }
                kept++;
            }
        }
    }
    // tail zeros (replaces d_out memset): positions [kept, OUTK)
    for (int p = kept + l; p < OUTK; p += 64)
        ob[p] = make_float4(0.f, 0.f, 0.f, 0.f);
}

// ---------------- host ----------------
extern "C" void kernel_launch(void* const* d_in, const int* in_sizes, int n_in,
                              void* d_out, int out_size, void* d_ws, size_t ws_size,
                              hipStream_t stream) {
    const float* cls     = (const float*)d_in[0];   // rpn_class  (B,N,2)
    const float* bbox    = (const float*)d_in[1];   // rpn_bbox   (B,N,4)
    const float* anchors = (const float*)d_in[2];   // anchors    (B,N,4)

    char* ws = (char*)d_ws;
    u32* hist1 = (u32*)(ws);                        // 131072
    u32* meta  = (u32*)(ws + 131072);               // 256 B (count @48+b, bucket m @56+b)
    float4* boxes = (float4*)(ws + 131328);         // 8*6016*16 = 770048 -> end 901376
    float* areas  = (float*)(ws + 901376);          // 8*6016*4  = 192512 -> end 1093888
    u64* Mt = (u64*)(ws + 1093888);                 // 8*32*2048*8 = 4194304 -> end 5288192
    // overlays on Mt (all dead before nms_mask writes Mt):
    u64* cand    = (u64*)(ws + 1093888);            // 8*16384*8 = 1 MB
    u64* grouped = (u64*)(ws + 1093888 + 1048576);  // 8*16384*8 = 1 MB
    size_t need = 1093888 + (size_t)NBATCH * MWORDS * MROWS * 8;
    if (ws_size < need) return;

    hipMemsetAsync(ws, 0, 131328, stream);          // hist + meta

    hist_kernel<<<dim3(64, NBATCH), 256, 0, stream>>>(cls, hist1);
    compact_kernel<<<dim3(64, NBATCH), 256, 0, stream>>>(cls, hist1, meta, cand);
    group_rank_kernel<<<NBATCH, 1024, 0, stream>>>(cand, meta, anchors, bbox, grouped, boxes, areas);
    nms_mask_kernel<<<dim3((NT2 + 3) / 4, NBATCH), 256, 0, stream>>>(boxes, areas, Mt);
    nms_seq_kernel<<<NBATCH, 64, 0, stream>>>(boxes, areas, Mt, (float*)d_out);
}

// Round 10
// 175.397 us; speedup vs baseline: 1.3011x; 1.3011x over previous
//
#include <hip/hip_runtime.h>
#include <cstdint>
#include <math.h>

#define NBATCH 8
#define NANCH 262144
#define TOPK 6000
#define OUTK 1000
#define CAP 16384
#define ROWS 6016          // TOPK padded to 94*64 (boxes/areas stride)
#define MROWS 2048         // masked NMS window: rows/cols with precomputed mask
#define MWORDS 32          // MROWS/64
#define NT2 528            // upper-tri tiles in window: 32*33/2
#define NBIN 8192          // fine-rank bins: (bucket-m)*2048 + float bits [19:9]

using u32 = uint32_t;
using u64 = unsigned long long;

// fine bin of a candidate key, given marginal 12-bit bucket m. Monotone non-decreasing
// in key (lexicographic on float bits [31:9], clamped at top) -> exact rank decomposition:
// rank(k) = #{k' : bin(k') > bin(k)} + #{k' : bin equal && k' > k}   (keys are unique).
__device__ inline u32 binof(u64 key, u32 m) {
    u32 hb  = (u32)(key >> 52);            // float bits [31:20] (>= m for all stored keys)
    u32 mid = (u32)(key >> 41) & 0x7FFu;   // float bits [19:9]
    u32 bi = (hb - m) * 2048u + mid;
    return bi > (NBIN - 1) ? (NBIN - 1) : bi;
}

// ---------------- coarse top-k threshold: one 12-bit histogram pass ----------------
__global__ void hist_kernel(const float* __restrict__ cls, u32* __restrict__ hist) {
    __shared__ u32 lh[4096];
    int b = blockIdx.y, t = threadIdx.x;
    for (int i = t; i < 4096; i += 256) lh[i] = 0;
    __syncthreads();
    const float4* p4 = (const float4*)(cls + (size_t)b * NANCH * 2);
    const int P = NANCH / 2;
    for (int p = blockIdx.x * 256 + t; p < P; p += gridDim.x * 256) {
        float4 v = p4[p];
        atomicAdd(&lh[__float_as_uint(v.y) >> 20], 1);
        atomicAdd(&lh[__float_as_uint(v.w) >> 20], 1);
    }
    __syncthreads();
    for (int i = t; i < 4096; i += 256) { u32 c = lh[i]; if (c) atomicAdd(&hist[b * 4096 + i], c); }
}

// ---------------- compact: inline threshold scan + LDS staging, 1 atomic/block ----------
__global__ void compact_kernel(const float* __restrict__ cls, const u32* __restrict__ hist,
                               u32* __restrict__ meta, u64* __restrict__ cand) {
    __shared__ u64 buf[4096];
    __shared__ u32 ts[256];
    __shared__ u32 thr, lc, gbase;
    int b = blockIdx.y, t = threadIdx.x;
    if (t == 0) lc = 0;
    const u32* h = hist + b * 4096;
    u32 s = 0;
    for (int k = 0; k < 16; k++) s += h[t * 16 + k];
    ts[t] = s; __syncthreads();
    u32 suf = 0;
    for (int t2 = t + 1; t2 < 256; t2++) suf += ts[t2];
    if (suf < TOPK && suf + s >= TOPK) {
        u32 a = suf;
        for (int k = 15; k >= 0; k--) {
            u32 c = h[t * 16 + k];
            if (a + c >= TOPK) { thr = (u32)(t * 16 + k) << 20; break; }
            a += c;
        }
    }
    __syncthreads();
    u32 T = thr;
    if (t == 0) meta[56 + b] = T >> 20;              // marginal bucket m (same in all blocks)
    const float4* p4 = (const float4*)(cls + (size_t)b * NANCH * 2);
    const int P = NANCH / 2;
    for (int p = blockIdx.x * 256 + t; p < P; p += gridDim.x * 256) {
        float4 v = p4[p];
        u32 k0 = __float_as_uint(v.y), k1 = __float_as_uint(v.w);
        u32 n0 = 2u * (u32)p, n1 = n0 + 1u;
        if (k0 >= T) { u32 q = atomicAdd(&lc, 1u); buf[q] = ((u64)k0 << 32) | (u32)(~n0); }
        if (k1 >= T) { u32 q = atomicAdd(&lc, 1u); buf[q] = ((u64)k1 << 32) | (u32)(~n1); }
    }
    __syncthreads();
    if (t == 0) gbase = atomicAdd(&meta[48 + b], lc);
    __syncthreads();
    u32 base = gbase, n = lc;
    for (u32 j = t; j < n; j += 256) {
        u32 d = base + j;
        if (d < CAP) cand[(size_t)b * CAP + d] = buf[j];
    }
}

// ---------------- group: LDS histogram + descending suffix scan + scatter ---------------
// One block per batch (1024 threads). LDS-local replacement for the old scan+scatter
// dispatch pair; NO latency-bound gathers here (those need the wide rank grid).
__global__ __launch_bounds__(1024) void group_kernel(
                            const u64* __restrict__ cand, const u32* __restrict__ meta,
                            u64* __restrict__ grouped) {
    __shared__ u32 lh[NBIN];                         // 32 KB: hist -> bases -> slot counters
    __shared__ u32 part[1024];
    __shared__ u32 wsum[16];
    int b = blockIdx.x, t = threadIdx.x;
    int wv = t >> 6, l = t & 63;
    u32 cnt = meta[48 + b]; if (cnt > CAP) cnt = CAP;
    u32 m = meta[56 + b];
    const u64* cb = cand + (size_t)b * CAP;
    u64* gb = grouped + (size_t)b * CAP;
    // 1) zero + build LDS histogram over stored keys
    #pragma unroll
    for (int k = 0; k < NBIN / 1024; k++) lh[t + k * 1024] = 0;
    __syncthreads();
    for (u32 i = t; i < cnt; i += 1024) atomicAdd(&lh[binof(cb[i], m)], 1u);
    __syncthreads();
    // 2) descending suffix scan: base[i] = #keys in bins > i. Thread t owns bins [8t, 8t+8).
    u32 s = 0;
    #pragma unroll
    for (int k = 0; k < 8; k++) s += lh[t * 8 + k];
    part[t] = s;
    __syncthreads();
    u32 wsuf = 0;                                    // suffix within wave (lanes > l)
    for (int k = l + 1; k < 64; k++) wsuf += part[(wv << 6) + k];
    if (l == 0) wsum[wv] = wsuf + part[wv << 6];     // total of this wave's 64 partials
    __syncthreads();
    u32 cur = wsuf;
    for (int k = wv + 1; k < 16; k++) cur += wsum[k];
    #pragma unroll
    for (int k = 7; k >= 0; k--) {                   // descending within my 8 bins
        u32 c = lh[t * 8 + k];
        lh[t * 8 + k] = cur;
        cur += c;
    }
    __syncthreads();
    // 3) scatter into bin-grouped order (slot = LDS atomic on base)
    for (u32 i = t; i < cnt; i += 1024) {
        u64 key = cb[i];
        u32 p = atomicAdd(&lh[binof(key, m)], 1u);
        if (p < CAP) gb[p] = key;                    // p < cnt always; defensive
    }
}

// ---------------- exact rank from bin-grouped array; decode + write boxes/areas ---------
// WIDE grid: the anchors/bbox gathers are random 16B reads - need chip-wide TLP to hide
// latency (R9 lesson: same code at 8 blocks = 80 us; at 512 blocks = ~10 us).
__global__ __launch_bounds__(256) void rank_kernel(
                            const u64* __restrict__ grouped, const u32* __restrict__ meta,
                            const float* __restrict__ anchors, const float* __restrict__ bbox,
                            float4* __restrict__ boxes, float* __restrict__ areas) {
    int b = blockIdx.y, t = threadIdx.x;
    int p = blockIdx.x * 256 + t;
    u32 cnt = meta[48 + b]; if (cnt > CAP) cnt = CAP;
    if (blockIdx.x == 0 && t < ROWS - TOPK) {   // zero-pad rows 6000..6015
        boxes[(size_t)b * ROWS + TOPK + t] = make_float4(0.f, 0.f, 0.f, 0.f);
        areas[(size_t)b * ROWS + TOPK + t] = 0.f;
    }
    if (p >= (int)cnt) return;
    u32 m = meta[56 + b];
    const u64* gb = grouped + (size_t)b * CAP;
    u64 key = gb[p];
    u32 bi = binof(key, m);
    int s = p;
    while (s > 0 && binof(gb[s - 1], m) == bi) s--;
    u32 r = 0;
    int q = s;
    while (q < (int)cnt) {
        u64 kq = gb[q];
        if (binof(kq, m) != bi) break;
        r += (kq > key) ? 1u : 0u;
        q++;
    }
    u32 rank = (u32)s + r;
    if (rank < TOPK) {
        u32 idx = ~(u32)(key & 0xFFFFFFFFull);
        size_t off = ((size_t)b * NANCH + idx) * 4;
        const float4 a = *(const float4*)(anchors + off);
        const float4 d = *(const float4*)(bbox + off);
        float h = a.z - a.x, w = a.w - a.y;
        float cy = a.x + 0.5f * h, cx = a.y + 0.5f * w;
        float dy = d.x * 0.1f, dx = d.y * 0.1f, dh = d.z * 0.2f, dw = d.w * 0.2f;
        cy = cy + dy * h; cx = cx + dx * w;
        h = h * (float)exp((double)dh);
        w = w * (float)exp((double)dw);
        float y1 = cy - 0.5f * h, x1 = cx - 0.5f * w;
        float y2 = cy + 0.5f * h, x2 = cx + 0.5f * w;
        y1 = fminf(fmaxf(y1, 0.f), 1.f); x1 = fminf(fmaxf(x1, 0.f), 1.f);
        y2 = fminf(fmaxf(y2, 0.f), 1.f); x2 = fminf(fmaxf(x2, 0.f), 1.f);
        boxes[(size_t)b * ROWS + rank] = make_float4(y1, x1, y2, x2);
        areas[(size_t)b * ROWS + rank] = (y2 - y1) * (x2 - x1);  // same rounding as reference
    }
}

// ---------------- cross-lane helpers ----------------
__device__ inline u64 wave_or64(u64 x) {
    u32 lo = (u32)x, hi = (u32)(x >> 32);
    lo |= __builtin_amdgcn_ds_swizzle(lo, 0x041F); hi |= __builtin_amdgcn_ds_swizzle(hi, 0x041F);
    lo |= __builtin_amdgcn_ds_swizzle(lo, 0x081F); hi |= __builtin_amdgcn_ds_swizzle(hi, 0x081F);
    lo |= __builtin_amdgcn_ds_swizzle(lo, 0x101F); hi |= __builtin_amdgcn_ds_swizzle(hi, 0x101F);
    lo |= __builtin_amdgcn_ds_swizzle(lo, 0x201F); hi |= __builtin_amdgcn_ds_swizzle(hi, 0x201F);
    lo |= __builtin_amdgcn_ds_swizzle(lo, 0x401F); hi |= __builtin_amdgcn_ds_swizzle(hi, 0x401F);
    u32 l0 = (u32)__builtin_amdgcn_readlane((int)lo, 0)  | (u32)__builtin_amdgcn_readlane((int)lo, 32);
    u32 h0 = (u32)__builtin_amdgcn_readlane((int)hi, 0)  | (u32)__builtin_amdgcn_readlane((int)hi, 32);
    return ((u64)h0 << 32) | l0;
}

// ---------------- NMS phase A: mask only the first MROWS rows/cols (528 tiles) ----------
// Exact decision: RN(inter/uni) > 0.7f  <=>  inter >= MID*uni (reals), MID = 0.7f + 2^-25.
// Fast f32 path: d = fma(uni,-0.7f,inter); |d| > 2^-18*uni => sign decides. Waves with any
// borderline col (rare) redo the whole tile with an exact-sign f64 fma.
// DIAGONAL tiles are stored COLUMN-major (lane l = column l: bit r = "row r suppresses
// col l", r < l) plus a self-bit at l — consumed only by nms_seq's fixpoint solve, which
// then needs no cross-lane readlane per step. Off-diag tiles stay row-major.
__global__ __launch_bounds__(256) void nms_mask_kernel(const float4* __restrict__ boxes,
                                                       const float* __restrict__ areas,
                                                       u64* __restrict__ Mt) {
    const float  EPS  = 3.8146972656e-06f;                       // 2^-18
    const double MIDD = (double)0.7f + 2.9802322387695312e-08;   // midpoint to nextup(0.7f)
    __shared__ float4 scol[4][64];
    __shared__ float  sare[4][64];
    int b = blockIdx.y;
    int wv = threadIdx.x >> 6, l = threadIdx.x & 63;
    int tid = blockIdx.x * 4 + wv;                               // linear upper-tri tile id
    if (tid >= NT2) return;                                      // wave-private LDS: safe
    // decode tid -> (cb, rt), rt <= cb, tid = cb*(cb+1)/2 + rt
    int cb = (int)((sqrt(8.0 * (double)tid + 1.0) - 1.0) * 0.5);
    while ((cb + 1) * (cb + 2) / 2 <= tid) cb++;
    while (cb * (cb + 1) / 2 > tid) cb--;
    int rt = tid - cb * (cb + 1) / 2;
    const float4* bx = boxes + (size_t)b * ROWS;
    const float*  ar = areas + (size_t)b * ROWS;
    scol[wv][l] = bx[cb * 64 + l];               // stage this wave's 64 col boxes (wave-sync)
    sare[wv][l] = ar[cb * 64 + l];
    int row = rt * 64 + l;
    float4 r4 = bx[row];
    float  rar = ar[row];
    u32 wlo = 0, whi = 0; u64 unc = 0;
    #pragma unroll
    for (int c = 63; c >= 0; c--) {              // full unroll, shift-or accumulation
        float4 c4 = scol[wv][c];                 // broadcast ds_read_b128 (no conflict)
        float  caf = sare[wv][c];
        float y1 = fmaxf(r4.x, c4.x), x1 = fmaxf(r4.y, c4.y);
        float y2 = fminf(r4.z, c4.z), x2 = fminf(r4.w, c4.w);
        float inter = fmaxf(y2 - y1, 0.f) * fmaxf(x2 - x1, 0.f);
        float uni = ((rar + caf) - inter) + 1e-9f;   // assoc matches reference
        float d = fmaf(uni, -0.7f, inter);
        float tt = uni * EPS;
        u32 sup = (d > tt) ? 1u : 0u;
        unc |= __ballot(fabsf(d) <= tt);
        if (c >= 32) whi = (whi << 1) | sup;
        else         wlo = (wlo << 1) | sup;
    }
    if (unc) {                                   // wave-uniform, rare
        wlo = 0; whi = 0;
        for (int c = 63; c >= 0; c--) {
            float4 c4 = scol[wv][c]; float caf = sare[wv][c];
            float y1 = fmaxf(r4.x, c4.x), x1 = fmaxf(r4.y, c4.y);
            float y2 = fminf(r4.z, c4.z), x2 = fminf(r4.w, c4.w);
            float inter = fmaxf(y2 - y1, 0.f) * fmaxf(x2 - x1, 0.f);
            float uni = ((rar + caf) - inter) + 1e-9f;
            double td = fma((double)uni, -MIDD, (double)inter);
            u32 sup = (td >= 0.0) ? 1u : 0u;     // exact sign; tie -> suppress (RN ties up)
            if (c >= 32) whi = (whi << 1) | sup;
            else         wlo = (wlo << 1) | sup;
        }
    }
    u64 w = ((u64)whi << 32) | wlo;
    if (cb == rt) {
        w &= (l < 63) ? (~0ull << (l + 1)) : 0ull;   // cols > row only (row-major view)
        // ballot-transpose: column c2's word = ballot over lanes(rows) of bit c2.
        u64 tw = 0;
        for (int c2 = 0; c2 < 64; c2++) {
            u64 bc = __ballot((u32)((w >> c2) & 1ull) != 0u);
            if (l == c2) tw = bc;
        }
        w = tw | (1ull << l);                        // self-bit (not below(l): harmless)
    }
    Mt[((size_t)b * MWORDS + cb) * MROWS + row] = w;           // coalesced full-line store
}

// ---------------- NMS phase B: masked sweep over first MROWS, exact fallback beyond -----
// Greedy kept-set per chunk = UNIQUE fixpoint of K = F(K), F(K) = {r in alive :
// col_r & K & below(r) == 0} (suppression is lower->higher index only, so the relation
// is a DAG; uniqueness by induction on row index). Fixpoint iteration from K0 = alive
// converges in <= max suppression-chain length (sparse suppression => ~1-3 iterations),
// replacing ~64 serial pick-steps per chunk with ~2-3 ballots.
__global__ __launch_bounds__(64) void nms_seq_kernel(const float4* __restrict__ boxes,
                                                     const float* __restrict__ areas,
                                                     const u64* __restrict__ Mt,
                                                     float* __restrict__ out) {
    const double MIDD = (double)0.7f + 2.9802322387695312e-08;
    __shared__ u32 keptIdx[1024];
    __shared__ float4 sbox[1024];
    __shared__ float  skar[1024];
    int b = blockIdx.x, l = threadIdx.x;
    const u64* Mb = Mt + (size_t)b * MWORDS * MROWS;  // Mb[word*MROWS + row]
    const float4* bx = boxes + (size_t)b * ROWS;
    const float*  ar = areas + (size_t)b * ROWS;
    float4* ob = (float4*)(out + (size_t)b * OUTK * 4);
    const u64 below = (1ull << l) - 1ull;             // bits strictly under this lane
    int kept = 0;
    u64 rw = 0;
    u64 dw0 = Mb[l];                                  // diag word (col-major) of chunk 0
    float4 vb0 = bx[l];  float va0 = ar[l];
    u64 X0 = Mb[(size_t)MROWS + l];                   // chunk-0 rows -> word 1
    u64 dw1 = Mb[(size_t)MROWS + 64 + l];             // diag word (col-major) of chunk 1
    float4 vb1 = bx[64 + l]; float va1 = ar[64 + l];
    u64 X1 = Mb[(size_t)2 * MROWS + 64 + l];          // chunk-1 rows -> word 2
    u64 gp = 0;                                       // per-lane PARTIAL lookahead OR
    for (int c = 0; c < MWORDS; c++) {
        int base = c * 64;
        u64 alive = ~rw;                              // all MROWS rows valid (< TOPK)
        u64 K = alive;                                // fixpoint solve (uniform value)
        while (true) {
            u64 Kn = alive & ~__ballot((dw0 & K & below) != 0ull);
            if (Kn == K) break;                       // true fixpoint = greedy kept set
            K = Kn;
        }
        int avail = OUTK - kept;
        int nk  = (int)__popcll(K);
        int pos = (int)__popcll(K & below);           // per-lane output offset
        u32 keptme = (u32)((K >> l) & 1ull);
        if (nk > avail) keptme &= (u32)(pos < avail); // exact greedy stop at OUTK
        if (keptme) {
            int opos = kept + pos;
            ob[opos] = vb0;
            keptIdx[opos] = (u32)(base + l);
            sbox[opos] = vb0;                         // mirror for potential fallback
            skar[opos] = va0;
        }
        kept += (nk < avail) ? nk : avail;
        if (kept >= OUTK || c + 1 >= MWORDS) break;
        rw = wave_or64((keptme ? X0 : 0ull) | gp);    // deferred xk + lookahead, one reduce
        __syncthreads();                              // keptIdx visible for gather
        u64 dw2 = 0, X2 = 0; float4 vb2 = make_float4(0.f, 0.f, 0.f, 0.f); float va2 = 0.f;
        u64 gpn = 0;
        if (c + 2 < MWORDS) {
            int nb2 = base + 128;
            dw2 = Mb[(size_t)(c + 2) * MROWS + nb2 + l];
            vb2 = bx[nb2 + l]; va2 = ar[nb2 + l];
            if (c + 3 < MWORDS) X2 = Mb[(size_t)(c + 3) * MROWS + nb2 + l];
            int K2g = kept;
            if (K2g > 0) {
                #pragma unroll
                for (int u = 0; u < 16; u++) {
                    int k = l + (u << 6);
                    u32 idx = keptIdx[(k < K2g) ? k : K2g - 1];
                    gpn |= Mb[(size_t)(c + 2) * MROWS + idx];
                }
            }
        }
        dw0 = dw1; X0 = X1; vb0 = vb1; va0 = va1;
        dw1 = dw2; X1 = X2; vb1 = vb2; va1 = va2;
        gp = gpn;
    }
    // exact on-demand fallback for rows beyond the masked window (expected never taken)
    if (kept < OUTK) {
        __syncthreads();
        for (int i = MROWS; i < TOPK && kept < OUTK; i++) {
            float4 c4 = bx[i]; float ca = ar[i];      // uniform load
            int sup = 0;
            for (int j = l; j < kept; j += 64) {
                float4 kb = sbox[j]; float ka = skar[j];
                float y1 = fmaxf(kb.x, c4.x), x1 = fmaxf(kb.y, c4.y);
                float y2 = fminf(kb.z, c4.z), x2 = fminf(kb.w, c4.w);
                float inter = fmaxf(y2 - y1, 0.f) * fmaxf(x2 - x1, 0.f);
                float uni = ((ka + ca) - inter) + 1e-9f;
                double td = fma((double)uni, -MIDD, (double)inter);
                sup |= (td >= 0.0) ? 1 : 0;
            }
            if (!__any(sup)) {
                if (l == 0) { ob[kept] = c4; sbox[kept] = c4; skar[kept] = ca; }
                kept++;
            }
        }
    }
    // tail zeros (replaces d_out memset): positions [kept, OUTK)
    for (int p = kept + l; p < OUTK; p += 64)
        ob[p] = make_float4(0.f, 0.f, 0.f, 0.f);
}

// ---------------- host ----------------
extern "C" void kernel_launch(void* const* d_in, const int* in_sizes, int n_in,
                              void* d_out, int out_size, void* d_ws, size_t ws_size,
                              hipStream_t stream) {
    const float* cls     = (const float*)d_in[0];   // rpn_class  (B,N,2)
    const float* bbox    = (const float*)d_in[1];   // rpn_bbox   (B,N,4)
    const float* anchors = (const float*)d_in[2];   // anchors    (B,N,4)

    char* ws = (char*)d_ws;
    u32* hist1 = (u32*)(ws);                        // 131072
    u32* meta  = (u32*)(ws + 131072);               // 256 B (count @48+b, bucket m @56+b)
    float4* boxes = (float4*)(ws + 131328);         // 8*6016*16 = 770048 -> end 901376
    float* areas  = (float*)(ws + 901376);          // 8*6016*4  = 192512 -> end 1093888
    u64* Mt = (u64*)(ws + 1093888);                 // 8*32*2048*8 = 4194304 -> end 5288192
    // overlays on Mt (all dead before nms_mask writes Mt):
    u64* cand    = (u64*)(ws + 1093888);            // 8*16384*8 = 1 MB
    u64* grouped = (u64*)(ws + 1093888 + 1048576);  // 8*16384*8 = 1 MB
    size_t need = 1093888 + (size_t)NBATCH * MWORDS * MROWS * 8;
    if (ws_size < need) return;

    hipMemsetAsync(ws, 0, 131328, stream);          // hist + meta

    hist_kernel<<<dim3(64, NBATCH), 256, 0, stream>>>(cls, hist1);
    compact_kernel<<<dim3(64, NBATCH), 256, 0, stream>>>(cls, hist1, meta, cand);
    group_kernel<<<NBATCH, 1024, 0, stream>>>(cand, meta, grouped);
    rank_kernel<<<dim3(CAP / 256, NBATCH), 256, 0, stream>>>(grouped, meta, anchors, bbox, boxes, areas);
    nms_mask_kernel<<<dim3((NT2 + 3) / 4, NBATCH), 256, 0, stream>>>(boxes, areas, Mt);
    nms_seq_kernel<<<NBATCH, 64, 0, stream>>>(boxes, areas, Mt, (float*)d_out);
}